// Round 8
// baseline (35.612 us; speedup 1.0000x reference)
//
#include <hip/hip_runtime.h>
#include <hip/hip_bf16.h>
#include <math.h>

// Engram scan. Fast path: prove on-device that every step is a "create"
// (feedback == 0) and write zeros; exact sequential fallback otherwise.
//
// Soundness (unchanged): n0==0 & B<=P => bank holds verbatim copies of
// earlier padrao rows and n<P always => every step creates unless a
// cos>=0.7 match exists among pairs (t, j<t). We flag at cos>=0.5 in bf16
// (rounding perturbs cosine <= ~0.004) -- conservative superset. Flag also
// set if n0!=0 or B>P. C-layout is the m89-verified mapping (col=lane&15,
// row=(lane>>4)*4+reg); k-permutation within lanes cancels; K-split halves
// are summed in LDS before thresholding (sum over full K preserved).
//
// r8 change (r7 = 31us, k_trimain ~25us): r7's trimain ran 528 blocks x 4
// waves = 2 waves/SIMD and a runtime-trip k-loop -- latency-bound: ~5 L2
// loads (~200cy) serialized per k-step with nothing to hide under.
//  1. 8 waves/block (512 thr): K-split x2 (w>>2) * M-split x4 (w&3)
//     -> 4 waves/SIMD (2x TLP). Halves combined via 16.6KB LDS, 1 barrier.
//  2. template<KH> compile-time trip count (D==1024 -> KH=8) + unroll
//     -> compiler pipelines loads across k-steps (counted vmcnt), 4x ILP.

#define LIMIAR_SIM 0.7f
#define LIMIAR_NOVO 0.3f
#define LR 0.01f
#define EPSV 1e-8f
#define CHECK_THRESH 0.5f   // conservative vs 0.7 decision threshold

typedef __attribute__((ext_vector_type(4))) float f32x4;
typedef __attribute__((ext_vector_type(8))) short bf16x8;

static __device__ inline unsigned short f2bf(float f) {
    unsigned int u = __float_as_uint(f);
    unsigned int r = (u + 0x7FFFu + ((u >> 16) & 1u)) >> 16;
    return (unsigned short)r;
}

// -- kernel 1: row norms + packed bf16 convert + nt zero-fill + flag init --
__global__ __launch_bounds__(256) void k_prep(const float* __restrict__ padrao,
                                              int B, int D, float* __restrict__ pn,
                                              unsigned short* __restrict__ xb,
                                              int do_conv,
                                              f32x4* __restrict__ out4,
                                              long long n4z, int do_zero,
                                              unsigned int* __restrict__ flag,
                                              const int* __restrict__ n0p,
                                              int force_flag) {
    __shared__ float red[4];
    int row = blockIdx.x;
    if (do_zero) {
        long long chunk = (n4z + gridDim.x - 1) / gridDim.x;
        long long zb = (long long)row * chunk;
        long long ze = zb + chunk; if (ze > n4z) ze = n4z;
        f32x4 z = {0.f, 0.f, 0.f, 0.f};
        for (long long i = zb + threadIdx.x; i < ze; i += 256)
            __builtin_nontemporal_store(z, &out4[i]);
    }
    const float* r = padrao + (long long)row * D;
    float s = 0.0f;
    if ((D & 3) == 0) {
        for (int k = threadIdx.x * 4; k < D; k += 1024) {
            float4 v = *(const float4*)(r + k);
            s += v.x * v.x + v.y * v.y + v.z * v.z + v.w * v.w;
            if (do_conv) {
                // packed layout: elem = ((row/16 * D/8 + k/8)*16 + row%16)*8 + k%8
                long long uoff = ((((long long)(row >> 4)) * (D >> 3) + (k >> 3)) * 16
                                  + (row & 15)) * 8 + (k & 7);
                ushort4 o;
                o.x = f2bf(v.x); o.y = f2bf(v.y); o.z = f2bf(v.z); o.w = f2bf(v.w);
                *(ushort4*)(xb + uoff) = o;
            }
        }
    } else {
        for (int k = threadIdx.x; k < D; k += 256) { float v = r[k]; s += v * v; }
    }
    for (int off = 32; off > 0; off >>= 1) s += __shfl_down(s, off);
    int wid = threadIdx.x >> 6, lane = threadIdx.x & 63;
    if (lane == 0) red[wid] = s;
    __syncthreads();
    if (threadIdx.x == 0) {
        float tot = red[0] + red[1] + red[2] + red[3];
        pn[row] = fmaxf(sqrtf(tot), EPSV);
        if (row == 0) *flag = (force_flag || (*n0p != 0)) ? 1u : 0u;
    }
}

// ------- kernel 2: MFMA tri-check, 8 waves = Ksplit2 x Msplit4 -------
// 64x64 tile/block; wave (wm,wk): rows [r0+16*wm,+16), K half wk.
// Contiguous 1KB fragment loads from the packed L2-resident buffer.
// KH = k-steps per half (compile-time for D=1024 -> pipelined loads).
template<int KH>
__global__ __launch_bounds__(512) void k_trimain(const unsigned short* __restrict__ xb,
                                                 const float* __restrict__ pn,
                                                 int B, int D,
                                                 unsigned int* __restrict__ flag) {
    __shared__ float red[4][16][65];   // 16.6 KB; <=2-way banks (free)
    int bid = blockIdx.x;
    int ti = (int)((sqrtf(8.0f * (float)bid + 1.0f) - 1.0f) * 0.5f);
    while ((ti + 1) * (ti + 2) / 2 <= bid) ++ti;
    while (ti * (ti + 1) / 2 > bid) --ti;
    int tj = bid - ti * (ti + 1) / 2;
    int r0 = ti * 64, c0 = tj * 64;
    int tid = threadIdx.x;
    int w = tid >> 6, l = tid & 63;
    int wm = w & 3, wk = w >> 2;
    int l15 = l & 15, lhi = l >> 4;
    const int kch = D >> 3;                 // 8-elem k-chunks per row-panel
    const bf16x8* gx = (const bf16x8*)xb;   // one unit = 16B
    long long rpan = (long long)((r0 >> 4) + wm) * kch;
    long long cpan0 = (long long)(c0 >> 4) * kch;
    f32x4 acc[4] = {};
    const int kh = KH ? KH : (D >> 6);      // k-steps per half (K=32 each)
    const int ks0 = wk * kh;
#pragma unroll 4
    for (int ks = 0; ks < kh; ++ks) {
        int kc = ((ks0 + ks) << 2) + lhi;   // this lane-group's 8-chunk
        bf16x8 a = gx[((rpan + kc) << 4) + l15];
        bf16x8 b[4];
#pragma unroll
        for (int j = 0; j < 4; ++j)
            b[j] = gx[((cpan0 + (long long)j * kch + kc) << 4) + l15];
#pragma unroll
        for (int j = 0; j < 4; ++j)
            acc[j] = __builtin_amdgcn_mfma_f32_16x16x32_bf16(a, b[j], acc[j], 0, 0, 0);
    }
    // ---- combine K-halves: wk=1 stores, wk=0 adds ----
    if (wk == 1) {
#pragma unroll
        for (int j = 0; j < 4; ++j)
#pragma unroll
            for (int r = 0; r < 4; ++r)
                red[wm][lhi * 4 + r][j * 16 + l15] = acc[j][r];
    }
    __syncthreads();
    if (wk == 0) {
#pragma unroll
        for (int j = 0; j < 4; ++j)
#pragma unroll
            for (int r = 0; r < 4; ++r)
                acc[j][r] += red[wm][lhi * 4 + r][j * 16 + l15];
        // threshold on registers; C layout (m89): col=l&15, row=lhi*4+r
        int trow = r0 + wm * 16 + lhi * 4;
        float pnr[4];
#pragma unroll
        for (int r = 0; r < 4; ++r) {
            int t = trow + r;
            pnr[r] = (t < B) ? pn[t] : 1.0f;
        }
        unsigned int hit = 0;
#pragma unroll
        for (int j = 0; j < 4; ++j) {
            int jj = c0 + j * 16 + l15;
            float pc = (jj < B) ? pn[jj] : 1.0f;
#pragma unroll
            for (int r = 0; r < 4; ++r) {
                int t = trow + r;
                if (t < B && jj < B && t > jj && acc[j][r] >= CHECK_THRESH * pnr[r] * pc)
                    hit = 1;
            }
        }
        if (hit) atomicOr(flag, 1u);
    }
}

// ------------- fp32 tri-check (ragged-shape fallback path) -------------
__global__ __launch_bounds__(256) void k_tricheck(const float* __restrict__ padrao,
                                                  const float* __restrict__ pn,
                                                  int B, int D,
                                                  unsigned int* __restrict__ flag) {
    __shared__ float As[64][65];
    __shared__ float Bs[64][65];
    int bid = blockIdx.x;
    int ti = (int)((sqrtf(8.0f * (float)bid + 1.0f) - 1.0f) * 0.5f);
    while ((ti + 1) * (ti + 2) / 2 <= bid) ++ti;
    while (ti * (ti + 1) / 2 > bid) --ti;
    int tj = bid - ti * (ti + 1) / 2;
    int r0 = ti * 64, c0 = tj * 64;
    int tid = threadIdx.x;
    int ty = tid >> 4, tx = tid & 15;
    float acc[4][4] = {};
    for (int k0 = 0; k0 < D; k0 += 64) {
        for (int s = tid; s < 64 * 64; s += 256) {
            int rr = s >> 6, cc = s & 63;
            int gc = k0 + cc;
            int gr = r0 + rr;
            As[rr][cc] = (gr < B && gc < D) ? padrao[(long long)gr * D + gc] : 0.0f;
            gr = c0 + rr;
            Bs[rr][cc] = (gr < B && gc < D) ? padrao[(long long)gr * D + gc] : 0.0f;
        }
        __syncthreads();
        for (int kk = 0; kk < 64; ++kk) {
            float a[4], b[4];
#pragma unroll
            for (int i = 0; i < 4; ++i) a[i] = As[ty * 4 + i][kk];
#pragma unroll
            for (int j = 0; j < 4; ++j) b[j] = Bs[tx * 4 + j][kk];
#pragma unroll
            for (int i = 0; i < 4; ++i)
#pragma unroll
                for (int j = 0; j < 4; ++j) acc[i][j] += a[i] * b[j];
        }
        __syncthreads();
    }
    unsigned int hit = 0;
    for (int i = 0; i < 4; ++i)
        for (int j = 0; j < 4; ++j) {
            int t = r0 + ty * 4 + i, jj = c0 + tx * 4 + j;
            if (t < B && jj < B && t > jj) {
                if (acc[i][j] >= CHECK_THRESH * pn[t] * pn[jj]) hit = 1;
            }
        }
    if (hit) atomicOr(flag, 1u);
}

// ---------------- zero kernels (ragged path only) ----------------
__global__ __launch_bounds__(256) void k_zero(f32x4* __restrict__ out, long long n4) {
    long long i = (long long)blockIdx.x * blockDim.x + threadIdx.x;
    long long stride = (long long)gridDim.x * blockDim.x;
    f32x4 z = {0.f, 0.f, 0.f, 0.f};
    for (; i < n4; i += stride) out[i] = z;
}
__global__ __launch_bounds__(256) void k_zero_s(float* __restrict__ out, long long n) {
    long long i = (long long)blockIdx.x * blockDim.x + threadIdx.x;
    long long stride = (long long)gridDim.x * blockDim.x;
    for (; i < n; i += stride) out[i] = 0.0f;
}

// ------- kernel 3: exact sequential fallback (runs only if flag set) -------
__global__ __launch_bounds__(1024) void k_fallback(
    const float* __restrict__ padrao, const float* __restrict__ erro,
    const float* __restrict__ protos0, const float* __restrict__ forca0,
    const int* __restrict__ n0p, const float* __restrict__ gainp,
    float* __restrict__ out, const float* __restrict__ pn_arr,
    float* __restrict__ wprotos, float* __restrict__ wforca,
    float* __restrict__ wprotn, const unsigned int* __restrict__ flag,
    int runnable, int B, int D, int P) {
    if (!runnable) return;
    if (*flag == 0) return;
    const int tid = threadIdx.x;
    const int NT = blockDim.x;
    __shared__ float rv[1024];
    __shared__ int ri[1024];
    for (long long i = tid; i < (long long)P * D; i += NT) wprotos[i] = protos0[i];
    for (int i = tid; i < P; i += NT) wforca[i] = forca0[i];
    __syncthreads();
    for (int j = tid; j < P; j += NT) {
        const float* r = wprotos + (long long)j * D;
        float s = 0.0f;
        for (int k = 0; k < D; ++k) s += r[k] * r[k];
        wprotn[j] = fmaxf(sqrtf(s), EPSV);
    }
    int n = *n0p;
    float gain = *gainp;
    __syncthreads();
    for (int t = 0; t < B; ++t) {
        const float* p = padrao + (long long)t * D;
        float pn = pn_arr[t];
        float best = -INFINITY; int bidx = 0;
        for (int j = tid; j < n; j += NT) {
            const float* r = wprotos + (long long)j * D;
            float d = 0.0f;
            for (int k = 0; k < D; ++k) d += r[k] * p[k];
            float sim = d / (wprotn[j] * pn);
            if (sim > best) { best = sim; bidx = j; }
        }
        rv[tid] = best; ri[tid] = bidx;
        __syncthreads();
        for (int off = NT >> 1; off > 0; off >>= 1) {
            if (tid < off) {
                float ov = rv[tid + off]; int oi = ri[tid + off];
                if (ov > rv[tid] || (ov == rv[tid] && oi < ri[tid])) { rv[tid] = ov; ri[tid] = oi; }
            }
            __syncthreads();
        }
        float max_sim = rv[0]; int idx = ri[0];
        __syncthreads();
        float err = erro[t];
        bool is_empty = (n == 0);
        bool do_reinf = (!is_empty) && (max_sim >= LIMIAR_SIM);
        bool do_create = is_empty || ((!do_reinf) && ((err > LIMIAR_NOVO) || (n < P)));
        if (do_create) {
            int cidx = n;
            if (n >= P) {
                float bv = INFINITY; int bi = 0;
                for (int j = tid; j < P; j += NT) {
                    float f = wforca[j];
                    if (f < bv) { bv = f; bi = j; }
                }
                rv[tid] = bv; ri[tid] = bi;
                __syncthreads();
                for (int off = NT >> 1; off > 0; off >>= 1) {
                    if (tid < off) {
                        float ov = rv[tid + off]; int oi = ri[tid + off];
                        if (ov < rv[tid] || (ov == rv[tid] && oi < ri[tid])) { rv[tid] = ov; ri[tid] = oi; }
                    }
                    __syncthreads();
                }
                cidx = ri[0];
                __syncthreads();
            }
            float* dst = wprotos + (long long)cidx * D;
            float* o = out + (long long)t * D;
            for (int k = tid; k < D; k += NT) { dst[k] = p[k]; o[k] = 0.0f; }
            if (tid == 0) { wforca[cidx] = 1.0f; wprotn[cidx] = pn; }
            if (n < P) n = n + 1;
        } else if (do_reinf) {
            float* dst = wprotos + (long long)idx * D;
            float fr_new = wforca[idx] + LR;
            float* o = out + (long long)t * D;
            float s2 = 0.0f;
            for (int k = tid; k < D; k += NT) {
                float np_ = (1.0f - LR) * dst[k] + LR * p[k];
                dst[k] = np_;
                o[k] = (np_ - p[k]) * fr_new * gain;
                s2 += np_ * np_;
            }
            rv[tid] = s2;
            __syncthreads();
            for (int off = NT >> 1; off > 0; off >>= 1) {
                if (tid < off) rv[tid] += rv[tid + off];
                __syncthreads();
            }
            if (tid == 0) { wforca[idx] = fr_new; wprotn[idx] = fmaxf(sqrtf(rv[0]), EPSV); }
        } else {
            const float* src = wprotos + (long long)idx * D;
            float fr = wforca[idx];
            float* o = out + (long long)t * D;
            for (int k = tid; k < D; k += NT) o[k] = (src[k] - p[k]) * fr * gain;
        }
        __syncthreads();
    }
}

extern "C" void kernel_launch(void* const* d_in, const int* in_sizes, int n_in,
                              void* d_out, int out_size, void* d_ws, size_t ws_size,
                              hipStream_t stream) {
    const float* padrao  = (const float*)d_in[0];
    const float* erro    = (const float*)d_in[1];
    const float* protos0 = (const float*)d_in[2];
    const float* forca0  = (const float*)d_in[3];
    const int*   n0p     = (const int*)d_in[5];
    const float* gainp   = (const float*)d_in[6];
    const int B = in_sizes[1];
    const int D = (B > 0) ? in_sizes[0] / B : 0;
    const int P = in_sizes[3];

    char* ws = (char*)d_ws;
    unsigned int* flag = (unsigned int*)ws;
    float* pn = (float*)(ws + 64);
    size_t off_xb = ((64 + (size_t)B * 4) + 63) & ~(size_t)63;
    unsigned short* xb = (unsigned short*)(ws + off_xb);
    size_t off_protos = (off_xb + (size_t)B * (size_t)D * 2 + 63) & ~(size_t)63;
    float* wprotos = (float*)(ws + off_protos);
    size_t off_forca = off_protos + (size_t)P * (size_t)D * 4;
    float* wforca = (float*)(ws + off_forca);
    size_t off_protn = off_forca + (size_t)P * 4;
    float* wprotn = (float*)(ws + off_protn);
    size_t need_total = off_protn + (size_t)P * 4;
    size_t need_fast = off_xb + (size_t)B * (size_t)D * 2;

    int runnable = (ws_size >= need_total) ? 1 : 0;
    int force_flag = (B > P) ? 1 : 0;
    int use_mfma = ((B % 64) == 0) && ((D % 128) == 0) && (ws_size >= need_fast)
                   && ((long long)out_size == (long long)B * D);

    int nT = (B + 63) / 64;
    int nblk = nT * (nT + 1) / 2;
    long long outN = (long long)out_size;

    if (use_mfma) {
        long long n4 = outN >> 2;   // outN = B*D, D%128==0 => divisible by 4
        k_prep<<<B, 256, 0, stream>>>(padrao, B, D, pn, xb, 1,
                                      (f32x4*)d_out, n4, 1, flag, n0p, force_flag);
        if (D == 1024)
            k_trimain<16><<<nblk, 512, 0, stream>>>(xb, pn, B, D, flag);
        else
            k_trimain<0><<<nblk, 512, 0, stream>>>(xb, pn, B, D, flag);
    } else {
        k_prep<<<B, 256, 0, stream>>>(padrao, B, D, pn, xb, 0,
                                      (f32x4*)d_out, 0, 0, flag, n0p, force_flag);
        k_tricheck<<<nblk, 256, 0, stream>>>(padrao, pn, B, D, flag);
        if ((outN & 3) == 0) {
            long long n4 = outN >> 2;
            int zb = (int)((n4 + 255) / 256); if (zb > 2048) zb = 2048; if (zb < 1) zb = 1;
            k_zero<<<zb, 256, 0, stream>>>((f32x4*)d_out, n4);
        } else {
            int zb = (int)((outN + 255) / 256); if (zb > 2048) zb = 2048; if (zb < 1) zb = 1;
            k_zero_s<<<zb, 256, 0, stream>>>((float*)d_out, outN);
        }
    }

    k_fallback<<<1, 1024, 0, stream>>>(padrao, erro, protos0, forca0, n0p, gainp,
                                       (float*)d_out, pn, wprotos, wforca, wprotn,
                                       flag, runnable, B, D, P);
}